// Round 2
// baseline (536.075 us; speedup 1.0000x reference)
//
#include <hip/hip_runtime.h>
#include <hip/hip_bf16.h>

typedef _Float16 half8 __attribute__((ext_vector_type(8)));
typedef float floatx4 __attribute__((ext_vector_type(4)));

// ---------------------------------------------------------------------------
// Kernel 1: Sinkhorn on the 128x128 matrix, factored form, v2.
// 256 threads: threads 0-127 own row i of A0 (in regs), threads 128-255 own
// column i (in regs, via LDS transpose). A0 never rescaled; iterate
//   r = 1/(A0 c)   [row threads]      c = 1/(A0^T r)   [col threads]
// Setup transcendentals split across all 256 threads; fast __logf/__expf
// (their ~1e-6 rel error is invisible under P's f16 rounding at 4.9e-4).
// 20-iter loop kept un-unrolled (~400 instr body) to avoid I-cache thrash.
// Final P[i][j] = r_i * A0[i][j] * c_j  -> f16 row-major in d_ws.
// ---------------------------------------------------------------------------
__global__ __launch_bounds__(256, 1) void sinkhorn128(
    const float* __restrict__ logits, const float* __restrict__ u,
    _Float16* __restrict__ Pout) {
    __shared__ float sA[128 * 129];           // +1 pad: conflict-free transpose
    __shared__ alignas(16) float sC[128];     // column scales c
    __shared__ alignas(16) float sR[128];     // row scales r
    const int t = threadIdx.x;                // 0..255
    const bool isRow = t < 128;
    const int idx = t & 127;

    // --- setup: thread t computes flat elements [t*64, t*64+64) of A0 ---
    #pragma unroll 4
    for (int j = 0; j < 64; ++j) {
        const int f = t * 64 + j;             // row = f>>7, col = f&127
        float lg = logits[f];
        float uu = u[f];
        float g  = -__logf(-__logf(uu + 1e-20f) + 1e-20f);  // NOISE_SCALE=1
        float la = (lg + g) * (1.0f / 3.0f);                 // TEMPERATURE=3
        la = fminf(10.0f, fmaxf(-10.0f, la));
        sA[(f >> 7) * 129 + (f & 127)] = __expf(la);
    }
    if (t < 128) sC[t] = 1.0f;
    __syncthreads();

    // --- register copy: row i for t<128, column i for t>=128 ---
    float av[128];
    if (isRow) {
        #pragma unroll
        for (int j = 0; j < 128; ++j) av[j] = sA[idx * 129 + j];
    } else {
        #pragma unroll
        for (int j = 0; j < 128; ++j) av[j] = sA[j * 129 + idx];
    }

    float ri = 1.0f;
    #pragma unroll 1
    for (int it = 0; it < 20; ++it) {
        if (isRow) {
            float s0 = 0.f, s1 = 0.f, s2 = 0.f, s3 = 0.f;
            #pragma unroll
            for (int j = 0; j < 128; j += 4) {
                float4 c4 = *reinterpret_cast<const float4*>(&sC[j]);
                s0 = fmaf(av[j + 0], c4.x, s0);
                s1 = fmaf(av[j + 1], c4.y, s1);
                s2 = fmaf(av[j + 2], c4.z, s2);
                s3 = fmaf(av[j + 3], c4.w, s3);
            }
            ri = 1.0f / ((s0 + s1) + (s2 + s3));
        }
        __syncthreads();              // row threads done reading sC
        if (isRow) sR[idx] = ri;
        __syncthreads();              // sR visible
        if (!isRow) {
            float s0 = 0.f, s1 = 0.f, s2 = 0.f, s3 = 0.f;
            #pragma unroll
            for (int j = 0; j < 128; j += 4) {
                float4 r4 = *reinterpret_cast<const float4*>(&sR[j]);
                s0 = fmaf(av[j + 0], r4.x, s0);
                s1 = fmaf(av[j + 1], r4.y, s1);
                s2 = fmaf(av[j + 2], r4.z, s2);
                s3 = fmaf(av[j + 3], r4.w, s3);
            }
            sC[idx] = 1.0f / ((s0 + s1) + (s2 + s3));
        }
        __syncthreads();              // new sC visible for next iteration
    }

    // P row idx = ri * av[j] * c[j] (row threads only), f16 row-major
    if (isRow) {
        #pragma unroll
        for (int j = 0; j < 128; j += 2) {
            union { _Float16 h[2]; unsigned int w; } pk;
            pk.h[0] = (_Float16)(ri * av[j + 0] * sC[j + 0]);
            pk.h[1] = (_Float16)(ri * av[j + 1] * sC[j + 1]);
            reinterpret_cast<unsigned int*>(Pout)[(idx * 128 + j) >> 1] = pk.w;
        }
    }
}

// ---------------------------------------------------------------------------
// Kernel 2: out = x @ P.T, streaming MFMA, no LDS, double-buffered x tiles.
// Each wave keeps ALL B fragments (P.T as f16) in 128 VGPRs, processes 16
// blocks of 16 rows. x split f16 hi + f16 lo (2 MFMAs) -> x-side error ~2^-22.
// A-frag: lane holds x[m0 + (l&15)][ks*32 + (l>>4)*8 + j]  (8 contiguous f32)
// B-frag: lane holds P[nt*16 + (l&15)][ks*32 + (l>>4)*8 + j] (8 contiguous f16)
// C/D:    lane l holds C[(l>>4)*4 + rr][l&15]
// VGPR budget ~245 (Bf 128 + 2x xa 64 + acc 32 + temps) -> 2 waves/SIMD.
// ---------------------------------------------------------------------------
__global__ __launch_bounds__(256, 2) void streamMatmul(
    const float* __restrict__ x, const _Float16* __restrict__ P,
    float* __restrict__ out) {
    const int lane = threadIdx.x & 63;
    const int wv   = threadIdx.x >> 6;
    const int gw   = blockIdx.x * 4 + wv;   // 0..2047
    const int r    = lane & 15;
    const int q    = lane >> 4;

    // Load all B fragments once: 4 k-steps x 8 n-tiles x 8 f16 = 128 VGPRs
    half8 Bf[4][8];
    #pragma unroll
    for (int ks = 0; ks < 4; ++ks)
        #pragma unroll
        for (int nt = 0; nt < 8; ++nt)
            Bf[ks][nt] = *reinterpret_cast<const half8*>(
                P + (nt * 16 + r) * 128 + ks * 32 + q * 8);

    const long baseRow = (long)gw * 256;    // 2048 waves x 256 rows = 524288
    const float* xbase = x + (baseRow + r) * 128 + q * 8;

    floatx4 xa0[4][2], xa1[4][2];

    auto issue = [&](int t, floatx4 (&xa)[4][2]) {
        const float* xp = xbase + (long)t * (16 * 128);
        #pragma unroll
        for (int ks = 0; ks < 4; ++ks) {
            xa[ks][0] = __builtin_nontemporal_load(
                reinterpret_cast<const floatx4*>(xp + ks * 32));
            xa[ks][1] = __builtin_nontemporal_load(
                reinterpret_cast<const floatx4*>(xp + ks * 32 + 4));
        }
    };

    auto compute_store = [&](int t, floatx4 (&xa)[4][2]) {
        floatx4 acc[8];
        #pragma unroll
        for (int nt = 0; nt < 8; ++nt) acc[nt] = (floatx4){0.f, 0.f, 0.f, 0.f};
        #pragma unroll
        for (int ks = 0; ks < 4; ++ks) {
            half8 ahi, alo;
            #pragma unroll
            for (int jj = 0; jj < 8; ++jj) {
                float f = (jj < 4) ? xa[ks][0][jj] : xa[ks][1][jj - 4];
                _Float16 h = (_Float16)f;
                ahi[jj] = h;
                alo[jj] = (_Float16)(f - (float)h);
            }
            #pragma unroll
            for (int nt = 0; nt < 8; ++nt) {
                acc[nt] = __builtin_amdgcn_mfma_f32_16x16x32_f16(
                    ahi, Bf[ks][nt], acc[nt], 0, 0, 0);
                acc[nt] = __builtin_amdgcn_mfma_f32_16x16x32_f16(
                    alo, Bf[ks][nt], acc[nt], 0, 0, 0);
            }
        }
        // lane l owns rows (q*4+rr), col (nt*16+r): 16 lanes x 4B = 64B segs
        float* op = out + (baseRow + t * 16 + q * 4) * 128 + r;
        #pragma unroll
        for (int nt = 0; nt < 8; ++nt)
            #pragma unroll
            for (int rr = 0; rr < 4; ++rr)
                __builtin_nontemporal_store(acc[nt][rr],
                                            op + rr * 128 + nt * 16);
    };

    issue(0, xa0);
    #pragma unroll 1
    for (int t = 0; t < 16; t += 2) {
        issue(t + 1, xa1);            // t+1 <= 15 always
        compute_store(t, xa0);
        if (t + 2 < 16) issue(t + 2, xa0);
        compute_store(t + 1, xa1);
    }
}

extern "C" void kernel_launch(void* const* d_in, const int* in_sizes, int n_in,
                              void* d_out, int out_size, void* d_ws, size_t ws_size,
                              hipStream_t stream) {
    (void)in_sizes; (void)n_in; (void)out_size; (void)ws_size;
    const float* x      = (const float*)d_in[0];  // [524288,128] f32
    const float* logits = (const float*)d_in[1];  // [128,128] f32
    const float* u      = (const float*)d_in[2];  // [128,128] f32
    float* out          = (float*)d_out;          // [524288,128] f32
    _Float16* P         = (_Float16*)d_ws;        // [128,128] f16 scratch

    sinkhorn128<<<1, 256, 0, stream>>>(logits, u, P);
    streamMatmul<<<512, 256, 0, stream>>>(x, P, out);
}